// Round 3
// baseline (630.990 us; speedup 1.0000x reference)
//
#include <hip/hip_runtime.h>
#include <hip/hip_bf16.h>

#define S_LEN 2048
#define NHEAD 16
#define HDIM 64
#define HID 1024
#define BATCH 2

typedef __attribute__((ext_vector_type(8))) short s16x8;
typedef __attribute__((ext_vector_type(4))) short s16x4;
typedef __attribute__((ext_vector_type(4))) float f32x4;

__device__ __forceinline__ short f2bf(float f) {
    union { __hip_bfloat16 b; short s; } u;
    u.b = __float2bfloat16(f);
    return u.s;
}
__device__ __forceinline__ float fexp2(float x) {
    return __builtin_amdgcn_exp2f(x);
}
__device__ __forceinline__ f32x4 mfma16(s16x8 a, s16x8 b, f32x4 c) {
    return __builtin_amdgcn_mfma_f32_16x16x32_bf16(a, b, c, 0, 0, 0);
}
__device__ __forceinline__ f32x4 mfma16k16(s16x4 a, s16x4 b, f32x4 c) {
    return __builtin_amdgcn_mfma_f32_16x16x16bf16_1k(a, b, c, 0, 0, 0);
}

// ---------------------------------------------------------------------------
// Kernel 1: fused QKV GEMM.  Y = x @ W.T  (W row-major [out,in], so both
// operands are k-contiguous).  M=4096, K=1024, fused N=3072 (wq|wk|wv).
// Q,K stored bf16 [b,h,s,d]; V stored TRANSPOSED bf16 [b,h,d,s].
// ---------------------------------------------------------------------------
__global__ __launch_bounds__(256) void qkv_gemm(
    const float* __restrict__ x, const float* __restrict__ wq,
    const float* __restrict__ wk, const float* __restrict__ wv,
    short* __restrict__ q_ws, short* __restrict__ k_ws, short* __restrict__ vt_ws)
{
    __shared__ short As[128][32];
    __shared__ short Bs[128][32];
    const int t = threadIdx.x;
    const int lane = t & 63, w = t >> 6;
    const int g = lane >> 4, r15 = lane & 15;
    const int wm = w >> 1, wn = w & 1;
    const int bid = blockIdx.x;
    const int mt = bid & 31, nt = bid >> 5;           // 32 x 24 blocks
    const int m0 = mt * 128, n0 = nt * 128;
    const int sel = n0 >> 10;                         // 0=q, 1=k, 2=v
    const float* W = (sel == 0) ? wq : ((sel == 1) ? wk : wv);
    const int nr0 = n0 & 1023;
    const int srow = t >> 3;                          // 0..31
    const int scol = (t & 7) * 4;                     // 0..28

    f32x4 acc[4][4] = {};

    for (int k0 = 0; k0 < 1024; k0 += 32) {
        __syncthreads();
        #pragma unroll
        for (int i = 0; i < 4; ++i) {
            int row = srow + i * 32;
            float4 va = *(const float4*)(x + (size_t)(m0 + row) * 1024 + k0 + scol);
            s16x4 sa = { f2bf(va.x), f2bf(va.y), f2bf(va.z), f2bf(va.w) };
            *(s16x4*)&As[row][scol] = sa;
            float4 vb = *(const float4*)(W + (size_t)(nr0 + row) * 1024 + k0 + scol);
            s16x4 sb = { f2bf(vb.x), f2bf(vb.y), f2bf(vb.z), f2bf(vb.w) };
            *(s16x4*)&Bs[row][scol] = sb;
        }
        __syncthreads();
        s16x8 af[4], bfr[4];
        #pragma unroll
        for (int mi = 0; mi < 4; ++mi)
            af[mi] = *(const s16x8*)&As[wm * 64 + mi * 16 + r15][g * 8];
        #pragma unroll
        for (int ni = 0; ni < 4; ++ni)
            bfr[ni] = *(const s16x8*)&Bs[wn * 64 + ni * 16 + r15][g * 8];
        #pragma unroll
        for (int mi = 0; mi < 4; ++mi)
            #pragma unroll
            for (int ni = 0; ni < 4; ++ni)
                acc[mi][ni] = mfma16(af[mi], bfr[ni], acc[mi][ni]);
    }

    // Epilogue: C/D layout col=lane&15, row=(lane>>4)*4+reg (m89/m91 verified)
    #pragma unroll
    for (int mi = 0; mi < 4; ++mi)
    #pragma unroll
    for (int ni = 0; ni < 4; ++ni) {
        f32x4 v = acc[mi][ni];
        #pragma unroll
        for (int reg = 0; reg < 4; ++reg) {
            int m  = m0 + wm * 64 + mi * 16 + g * 4 + reg;
            int ng = n0 + wn * 64 + ni * 16 + r15;
            int nn = ng & 1023;
            int b = m >> 11, s = m & 2047;
            int h = nn >> 6, d = nn & 63;
            short val = f2bf(v[reg]);
            if (sel == 0)
                q_ws[((size_t)(b * NHEAD + h) * S_LEN + s) * HDIM + d] = val;
            else if (sel == 1)
                k_ws[((size_t)(b * NHEAD + h) * S_LEN + s) * HDIM + d] = val;
            else
                vt_ws[((size_t)(b * NHEAD + h) * HDIM + d) * S_LEN + s] = val;
        }
    }
}

// ---------------------------------------------------------------------------
// Kernel 2: causal flash attention.  4 independent waves per block, each wave
// owns 16 q-rows.  NO LDS, NO barriers: K and V^T MFMA fragments are loaded
// directly from global (L1/L2-resident: 256KB K + 256KB V per head).
// Swapped QK^T (16x16x32): lane(g,r15) gets P[key=f*16+g*4+reg][q=r15] --
// which IS the B-fragment layout of mfma_16x16x16, so PV needs no shuffles.
// Only the diagonal KV tile is masked; its key-blocks f>w are skipped.
// ---------------------------------------------------------------------------
__global__ __launch_bounds__(256) void attn_kernel(
    const short* __restrict__ q_ws, const short* __restrict__ k_ws,
    const short* __restrict__ vt_ws, short* __restrict__ attn_ws)
{
    const int t = threadIdx.x;
    const int lane = t & 63;
    const int w = t >> 6;
    const int g = lane >> 4, r15 = lane & 15;
    const int bid = blockIdx.x;
    const int qt = bid & 31;
    const int bh = bid >> 5;                       // b*16+h
    const int q0 = qt * 64;
    const int qg = q0 + w * 16 + r15;              // this lane's q row
    const size_t base = (size_t)bh * S_LEN * HDIM; // same count for k and vt
    const float KSC = 0.18033688f;                 // 0.125 * log2(e)

    s16x8 qf[2];
    #pragma unroll
    for (int c = 0; c < 2; ++c)
        qf[c] = *(const s16x8*)(q_ws + base + (size_t)qg * HDIM + c * 32 + g * 8);

    f32x4 o[4] = {};
    float mrun = -1e30f, lrun = 0.f;

    // ---- full (unmasked) KV tiles ----
    for (int kt = 0; kt < qt; ++kt) {
        const int kv0 = kt * 64;
        s16x8 kf[4][2];
        #pragma unroll
        for (int f = 0; f < 4; ++f)
            #pragma unroll
            for (int c = 0; c < 2; ++c)
                kf[f][c] = *(const s16x8*)(k_ws + base +
                    (size_t)(kv0 + f * 16 + r15) * HDIM + c * 32 + g * 8);
        s16x4 vf[4][4];
        #pragma unroll
        for (int f2 = 0; f2 < 4; ++f2)
            #pragma unroll
            for (int f = 0; f < 4; ++f)
                vf[f2][f] = *(const s16x4*)(vt_ws + base +
                    (size_t)(f2 * 16 + r15) * S_LEN + kv0 + f * 16 + g * 4);

        float p[4][4];
        float pmax = -1e30f;
        __builtin_amdgcn_s_setprio(1);
        #pragma unroll
        for (int f = 0; f < 4; ++f) {
            f32x4 z = { 0.f, 0.f, 0.f, 0.f };
            z = mfma16(kf[f][0], qf[0], z);
            z = mfma16(kf[f][1], qf[1], z);
            #pragma unroll
            for (int reg = 0; reg < 4; ++reg) {
                float sv = z[reg] * KSC;
                p[f][reg] = sv;
                pmax = fmaxf(pmax, sv);
            }
        }
        __builtin_amdgcn_s_setprio(0);
        pmax = fmaxf(pmax, __shfl_xor(pmax, 16));
        pmax = fmaxf(pmax, __shfl_xor(pmax, 32));
        float newm = fmaxf(mrun, pmax);
        float sc = fexp2(mrun - newm);
        float rsum = 0.f;
        s16x4 pb[4];
        #pragma unroll
        for (int f = 0; f < 4; ++f) {
            #pragma unroll
            for (int reg = 0; reg < 4; ++reg) {
                float e = fexp2(p[f][reg] - newm);
                rsum += e;
                pb[f][reg] = f2bf(e);
            }
        }
        rsum += __shfl_xor(rsum, 16);
        rsum += __shfl_xor(rsum, 32);
        lrun = lrun * sc + rsum;
        mrun = newm;
        #pragma unroll
        for (int f2 = 0; f2 < 4; ++f2) o[f2] *= sc;

        __builtin_amdgcn_s_setprio(1);
        #pragma unroll
        for (int f2 = 0; f2 < 4; ++f2)
            #pragma unroll
            for (int f = 0; f < 4; ++f)
                o[f2] = mfma16k16(vf[f2][f], pb[f], o[f2]);
        __builtin_amdgcn_s_setprio(0);
    }

    // ---- diagonal (masked) tile: only key-blocks f <= w contribute ----
    {
        const int kv0 = qt * 64;
        const int fend = w + 1;
        s16x8 kf[4][2];
        for (int f = 0; f < fend; ++f)
            #pragma unroll
            for (int c = 0; c < 2; ++c)
                kf[f][c] = *(const s16x8*)(k_ws + base +
                    (size_t)(kv0 + f * 16 + r15) * HDIM + c * 32 + g * 8);
        s16x4 vf[4][4];
        #pragma unroll
        for (int f2 = 0; f2 < 4; ++f2)
            for (int f = 0; f < fend; ++f)
                vf[f2][f] = *(const s16x4*)(vt_ws + base +
                    (size_t)(f2 * 16 + r15) * S_LEN + kv0 + f * 16 + g * 4);

        float p[4][4];
        float pmax = -1e30f;
        __builtin_amdgcn_s_setprio(1);
        for (int f = 0; f < fend; ++f) {
            f32x4 z = { 0.f, 0.f, 0.f, 0.f };
            z = mfma16(kf[f][0], qf[0], z);
            z = mfma16(kf[f][1], qf[1], z);
            #pragma unroll
            for (int reg = 0; reg < 4; ++reg) {
                float sv = z[reg] * KSC;
                // mask only in the f==w block; f<w keys are all <= q
                if (f == w) sv = (g * 4 + reg > r15) ? -1e30f : sv;
                p[f][reg] = sv;
                pmax = fmaxf(pmax, sv);
            }
        }
        __builtin_amdgcn_s_setprio(0);
        pmax = fmaxf(pmax, __shfl_xor(pmax, 16));
        pmax = fmaxf(pmax, __shfl_xor(pmax, 32));
        float newm = fmaxf(mrun, pmax);
        float sc = fexp2(mrun - newm);
        float rsum = 0.f;
        s16x4 pb[4];
        for (int f = 0; f < fend; ++f) {
            #pragma unroll
            for (int reg = 0; reg < 4; ++reg) {
                float e = fexp2(p[f][reg] - newm);
                rsum += e;
                pb[f][reg] = f2bf(e);
            }
        }
        rsum += __shfl_xor(rsum, 16);
        rsum += __shfl_xor(rsum, 32);
        lrun = lrun * sc + rsum;
        mrun = newm;
        #pragma unroll
        for (int f2 = 0; f2 < 4; ++f2) o[f2] *= sc;

        __builtin_amdgcn_s_setprio(1);
        #pragma unroll
        for (int f2 = 0; f2 < 4; ++f2)
            for (int f = 0; f < fend; ++f)
                o[f2] = mfma16k16(vf[f2][f], pb[f], o[f2]);
        __builtin_amdgcn_s_setprio(0);
    }

    float inv = 1.f / (lrun + 1e-8f);
    const int b = bh >> 4, h = bh & 15;
    size_t obase = ((size_t)b * S_LEN + qg) * HID + h * HDIM + g * 4;
    #pragma unroll
    for (int f2 = 0; f2 < 4; ++f2) {
        s16x4 ov = { f2bf(o[f2][0] * inv), f2bf(o[f2][1] * inv),
                     f2bf(o[f2][2] * inv), f2bf(o[f2][3] * inv) };
        *(s16x4*)(attn_ws + obase + f2 * 16) = ov;
    }
}

// ---------------------------------------------------------------------------
// Kernel 3: out = attn(bf16) @ wo.T  -> fp32 d_out.  M=4096,N=1024,K=1024.
// ---------------------------------------------------------------------------
__global__ __launch_bounds__(256) void wo_gemm(
    const short* __restrict__ attn, const float* __restrict__ wo,
    float* __restrict__ out)
{
    __shared__ short As[128][32];
    __shared__ short Bs[128][32];
    const int t = threadIdx.x;
    const int lane = t & 63, w = t >> 6;
    const int g = lane >> 4, r15 = lane & 15;
    const int wm = w >> 1, wn = w & 1;
    const int bid = blockIdx.x;
    const int mt = bid & 31, nt = bid >> 5;            // 32 x 8 blocks
    const int m0 = mt * 128, n0 = nt * 128;
    const int arow = t >> 2, acol = (t & 3) * 8;
    const int srow = t >> 3, scol = (t & 7) * 4;

    f32x4 acc[4][4] = {};

    for (int k0 = 0; k0 < 1024; k0 += 32) {
        __syncthreads();
        #pragma unroll
        for (int i = 0; i < 2; ++i) {
            int row = arow + i * 64;
            *(s16x8*)&As[row][acol] =
                *(const s16x8*)(attn + (size_t)(m0 + row) * 1024 + k0 + acol);
        }
        #pragma unroll
        for (int i = 0; i < 4; ++i) {
            int row = srow + i * 32;
            float4 vb = *(const float4*)(wo + (size_t)(n0 + row) * 1024 + k0 + scol);
            s16x4 sb = { f2bf(vb.x), f2bf(vb.y), f2bf(vb.z), f2bf(vb.w) };
            *(s16x4*)&Bs[row][scol] = sb;
        }
        __syncthreads();
        s16x8 af[4], bfr[4];
        #pragma unroll
        for (int mi = 0; mi < 4; ++mi)
            af[mi] = *(const s16x8*)&As[wm * 64 + mi * 16 + r15][g * 8];
        #pragma unroll
        for (int ni = 0; ni < 4; ++ni)
            bfr[ni] = *(const s16x8*)&Bs[wn * 64 + ni * 16 + r15][g * 8];
        #pragma unroll
        for (int mi = 0; mi < 4; ++mi)
            #pragma unroll
            for (int ni = 0; ni < 4; ++ni)
                acc[mi][ni] = mfma16(af[mi], bfr[ni], acc[mi][ni]);
    }

    #pragma unroll
    for (int mi = 0; mi < 4; ++mi)
    #pragma unroll
    for (int ni = 0; ni < 4; ++ni) {
        #pragma unroll
        for (int reg = 0; reg < 4; ++reg) {
            int m = m0 + wm * 64 + mi * 16 + g * 4 + reg;
            int n = n0 + wn * 64 + ni * 16 + r15;
            out[(size_t)m * 1024 + n] = acc[mi][ni][reg];
        }
    }
}

extern "C" void kernel_launch(void* const* d_in, const int* in_sizes, int n_in,
                              void* d_out, int out_size, void* d_ws, size_t ws_size,
                              hipStream_t stream) {
    const float* x  = (const float*)d_in[0];
    const float* wq = (const float*)d_in[1];
    const float* wk = (const float*)d_in[2];
    const float* wv = (const float*)d_in[3];
    const float* wo = (const float*)d_in[4];
    float* out = (float*)d_out;

    const size_t ELEMS = (size_t)BATCH * S_LEN * HID;   // 4096*1024
    short* q_ws    = (short*)d_ws;
    short* k_ws    = q_ws + ELEMS;
    short* vt_ws   = k_ws + ELEMS;
    short* attn_ws = vt_ws + ELEMS;

    qkv_gemm<<<dim3(768), dim3(256), 0, stream>>>(x, wq, wk, wv, q_ws, k_ws, vt_ws);
    attn_kernel<<<dim3(1024), dim3(256), 0, stream>>>(q_ws, k_ws, vt_ws, attn_ws);
    wo_gemm<<<dim3(256), dim3(256), 0, stream>>>(attn_ws, wo, out);
}

// Round 4
// 195.990 us; speedup vs baseline: 3.2195x; 3.2195x over previous
//
#include <hip/hip_runtime.h>
#include <hip/hip_bf16.h>

#define S_LEN 2048
#define NHEAD 16
#define HDIM 64
#define HID 1024
#define BATCH 2

typedef __attribute__((ext_vector_type(8))) short s16x8;
typedef __attribute__((ext_vector_type(4))) short s16x4;
typedef __attribute__((ext_vector_type(4))) float f32x4;

__device__ __forceinline__ short f2bf(float f) {
    union { __hip_bfloat16 b; short s; } u;
    u.b = __float2bfloat16(f);
    return u.s;
}
__device__ __forceinline__ float fexp2(float x) {
    return __builtin_amdgcn_exp2f(x);
}
__device__ __forceinline__ f32x4 mfma16(s16x8 a, s16x8 b, f32x4 c) {
    return __builtin_amdgcn_mfma_f32_16x16x32_bf16(a, b, c, 0, 0, 0);
}
__device__ __forceinline__ f32x4 mfma16k16(s16x4 a, s16x4 b, f32x4 c) {
    return __builtin_amdgcn_mfma_f32_16x16x16bf16_1k(a, b, c, 0, 0, 0);
}

// ---------------------------------------------------------------------------
// Kernel 1: fused QKV GEMM (unchanged from R1).
// Q,K stored bf16 [b,h,s,d]; V stored TRANSPOSED bf16 [b,h,d,s].
// ---------------------------------------------------------------------------
__global__ __launch_bounds__(256) void qkv_gemm(
    const float* __restrict__ x, const float* __restrict__ wq,
    const float* __restrict__ wk, const float* __restrict__ wv,
    short* __restrict__ q_ws, short* __restrict__ k_ws, short* __restrict__ vt_ws)
{
    __shared__ short As[128][32];
    __shared__ short Bs[128][32];
    const int t = threadIdx.x;
    const int lane = t & 63, w = t >> 6;
    const int g = lane >> 4, r15 = lane & 15;
    const int wm = w >> 1, wn = w & 1;
    const int bid = blockIdx.x;
    const int mt = bid & 31, nt = bid >> 5;           // 32 x 24 blocks
    const int m0 = mt * 128, n0 = nt * 128;
    const int sel = n0 >> 10;                         // 0=q, 1=k, 2=v
    const float* W = (sel == 0) ? wq : ((sel == 1) ? wk : wv);
    const int nr0 = n0 & 1023;
    const int srow = t >> 3;
    const int scol = (t & 7) * 4;

    f32x4 acc[4][4] = {};

    for (int k0 = 0; k0 < 1024; k0 += 32) {
        __syncthreads();
        #pragma unroll
        for (int i = 0; i < 4; ++i) {
            int row = srow + i * 32;
            float4 va = *(const float4*)(x + (size_t)(m0 + row) * 1024 + k0 + scol);
            s16x4 sa = { f2bf(va.x), f2bf(va.y), f2bf(va.z), f2bf(va.w) };
            *(s16x4*)&As[row][scol] = sa;
            float4 vb = *(const float4*)(W + (size_t)(nr0 + row) * 1024 + k0 + scol);
            s16x4 sb = { f2bf(vb.x), f2bf(vb.y), f2bf(vb.z), f2bf(vb.w) };
            *(s16x4*)&Bs[row][scol] = sb;
        }
        __syncthreads();
        s16x8 af[4], bfr[4];
        #pragma unroll
        for (int mi = 0; mi < 4; ++mi)
            af[mi] = *(const s16x8*)&As[wm * 64 + mi * 16 + r15][g * 8];
        #pragma unroll
        for (int ni = 0; ni < 4; ++ni)
            bfr[ni] = *(const s16x8*)&Bs[wn * 64 + ni * 16 + r15][g * 8];
        #pragma unroll
        for (int mi = 0; mi < 4; ++mi)
            #pragma unroll
            for (int ni = 0; ni < 4; ++ni)
                acc[mi][ni] = mfma16(af[mi], bfr[ni], acc[mi][ni]);
    }

    #pragma unroll
    for (int mi = 0; mi < 4; ++mi)
    #pragma unroll
    for (int ni = 0; ni < 4; ++ni) {
        f32x4 v = acc[mi][ni];
        #pragma unroll
        for (int reg = 0; reg < 4; ++reg) {
            int m  = m0 + wm * 64 + mi * 16 + g * 4 + reg;
            int ng = n0 + wn * 64 + ni * 16 + r15;
            int nn = ng & 1023;
            int b = m >> 11, s = m & 2047;
            int h = nn >> 6, d = nn & 63;
            short val = f2bf(v[reg]);
            if (sel == 0)
                q_ws[((size_t)(b * NHEAD + h) * S_LEN + s) * HDIM + d] = val;
            else if (sel == 1)
                k_ws[((size_t)(b * NHEAD + h) * S_LEN + s) * HDIM + d] = val;
            else
                vt_ws[((size_t)(b * NHEAD + h) * HDIM + d) * S_LEN + s] = val;
        }
    }
}

// ---------------------------------------------------------------------------
// Kernel 2: causal flash attention.  Q-tile = 128 rows/block, 4 waves, each
// wave owns rows {q0+w*16+r15, q0+64+w*16+r15} (m=0,1) so diagonal work is
// balanced.  K/V^T staged in double-buffered XOR-swizzled LDS (T14 split:
// global->reg before compute, ds_write after, 1 barrier/tile).
// Swapped QK^T (16x16x32) -> P's C-layout IS the B-frag of 16x16x16 -> PV
// needs no shuffles.  exp2-domain online softmax.
// ---------------------------------------------------------------------------
__global__ __launch_bounds__(256) void attn_kernel(
    const short* __restrict__ q_ws, const short* __restrict__ k_ws,
    const short* __restrict__ vt_ws, short* __restrict__ attn_ws)
{
    __shared__ short Ks[2][64][64];
    __shared__ short Vts[2][64][64];
    const int t = threadIdx.x;
    const int lane = t & 63;
    const int w = t >> 6;
    const int g = lane >> 4, r15 = lane & 15;
    const int bid = blockIdx.x;
    const int lb = (bid & 7) * 64 + (bid >> 3);   // XCD-chunked swizzle (512%8==0)
    const int qtile = lb & 15;
    const int bh = lb >> 4;
    const int q0 = qtile * 128;
    const size_t base = (size_t)bh * S_LEN * HDIM;
    const float KSC = 0.18033688f;                // 0.125 * log2(e)
    const int swr = (r15 & 7) << 3;

    // staging geometry: 2 chunks of 16B per thread per array
    const int u1 = t + 256;
    const int r0 = t >> 3,  c0 = (t & 7) * 8;
    const int r1 = u1 >> 3, c1 = (u1 & 7) * 8;
    const int cx0 = c0 ^ ((r0 & 7) << 3);
    const int cx1 = c1 ^ ((r1 & 7) << 3);

    // q fragments: rows q0 + m*64 + w*16 + r15
    s16x8 qf[2][2];
    #pragma unroll
    for (int m = 0; m < 2; ++m)
        #pragma unroll
        for (int c = 0; c < 2; ++c)
            qf[m][c] = *(const s16x8*)(q_ws + base +
                (size_t)(q0 + m * 64 + w * 16 + r15) * HDIM + c * 32 + g * 8);

    f32x4 o[2][4] = {};
    float mrun[2] = { -1e30f, -1e30f }, lrun[2] = { 0.f, 0.f };

    const int nt = 2 * qtile + 2;

    // prologue: stage tile 0 into buffer 0
    {
        *(s16x8*)&Ks[0][r0][cx0]  = *(const s16x8*)(k_ws  + base + (size_t)r0 * HDIM + c0);
        *(s16x8*)&Ks[0][r1][cx1]  = *(const s16x8*)(k_ws  + base + (size_t)r1 * HDIM + c1);
        *(s16x8*)&Vts[0][r0][cx0] = *(const s16x8*)(vt_ws + base + (size_t)r0 * S_LEN + c0);
        *(s16x8*)&Vts[0][r1][cx1] = *(const s16x8*)(vt_ws + base + (size_t)r1 * S_LEN + c1);
    }
    __syncthreads();

    for (int kt = 0; kt < nt; ++kt) {
        const int cur = kt & 1;
        const int kv0 = kt * 64;
        const bool pre = (kt + 1 < nt);
        s16x8 ka, kb, va, vb;
        if (pre) {
            const int kn = kv0 + 64;
            ka = *(const s16x8*)(k_ws  + base + (size_t)(kn + r0) * HDIM + c0);
            kb = *(const s16x8*)(k_ws  + base + (size_t)(kn + r1) * HDIM + c1);
            va = *(const s16x8*)(vt_ws + base + (size_t)r0 * S_LEN + kn + c0);
            vb = *(const s16x8*)(vt_ws + base + (size_t)r1 * S_LEN + kn + c1);
        }

        if (kt < nt - 2) {
            // ---------------- full (unmasked) tile ----------------
            s16x8 kfa[4][2];
            #pragma unroll
            for (int f = 0; f < 4; ++f)
                #pragma unroll
                for (int c = 0; c < 2; ++c)
                    kfa[f][c] = *(const s16x8*)&Ks[cur][f * 16 + r15][(c * 32 + g * 8) ^ swr];
            s16x4 vfa[4][4];
            #pragma unroll
            for (int f2 = 0; f2 < 4; ++f2)
                #pragma unroll
                for (int f = 0; f < 4; ++f)
                    vfa[f2][f] = *(const s16x4*)&Vts[cur][f2 * 16 + r15][(f * 16 + g * 4) ^ swr];

            #pragma unroll
            for (int m = 0; m < 2; ++m) {
                float p[4][4];
                float pmax = -1e30f;
                __builtin_amdgcn_s_setprio(1);
                #pragma unroll
                for (int f = 0; f < 4; ++f) {
                    f32x4 z = { 0.f, 0.f, 0.f, 0.f };
                    z = mfma16(kfa[f][0], qf[m][0], z);
                    z = mfma16(kfa[f][1], qf[m][1], z);
                    #pragma unroll
                    for (int reg = 0; reg < 4; ++reg) {
                        float sv = z[reg] * KSC;
                        p[f][reg] = sv;
                        pmax = fmaxf(pmax, sv);
                    }
                }
                __builtin_amdgcn_s_setprio(0);
                pmax = fmaxf(pmax, __shfl_xor(pmax, 16));
                pmax = fmaxf(pmax, __shfl_xor(pmax, 32));
                float newm = fmaxf(mrun[m], pmax);
                float sc = fexp2(mrun[m] - newm);
                float rsum = 0.f;
                s16x4 pb[4];
                #pragma unroll
                for (int f = 0; f < 4; ++f)
                    #pragma unroll
                    for (int reg = 0; reg < 4; ++reg) {
                        float e = fexp2(p[f][reg] - newm);
                        rsum += e;
                        pb[f][reg] = f2bf(e);
                    }
                rsum += __shfl_xor(rsum, 16);
                rsum += __shfl_xor(rsum, 32);
                lrun[m] = lrun[m] * sc + rsum;
                mrun[m] = newm;
                #pragma unroll
                for (int f2 = 0; f2 < 4; ++f2) o[m][f2] *= sc;
                __builtin_amdgcn_s_setprio(1);
                #pragma unroll
                for (int f2 = 0; f2 < 4; ++f2)
                    #pragma unroll
                    for (int f = 0; f < 4; ++f)
                        o[m][f2] = mfma16k16(vfa[f2][f], pb[f], o[m][f2]);
                __builtin_amdgcn_s_setprio(0);
            }
        } else {
            // ---------------- diagonal (partially masked) tiles ----------------
            const int dm0 = (q0 + w * 16 - kv0) >> 4;     // multiple-of-16 diff
            const int dm1 = dm0 + 4;
            const int fe0 = dm0 < 0 ? 0 : (dm0 + 1 > 4 ? 4 : dm0 + 1);
            const int fe1 = dm1 + 1 > 4 ? 4 : dm1 + 1;
            const int fmax = fe1 > fe0 ? fe1 : fe0;

            s16x8 kfa[4][2];
            #pragma unroll
            for (int f = 0; f < 4; ++f)
                if (f < fmax)
                    #pragma unroll
                    for (int c = 0; c < 2; ++c)
                        kfa[f][c] = *(const s16x8*)&Ks[cur][f * 16 + r15][(c * 32 + g * 8) ^ swr];
            s16x4 vfa[4][4];
            #pragma unroll
            for (int f2 = 0; f2 < 4; ++f2)
                #pragma unroll
                for (int f = 0; f < 4; ++f)
                    if (f < fmax)
                        vfa[f2][f] = *(const s16x4*)&Vts[cur][f2 * 16 + r15][(f * 16 + g * 4) ^ swr];

            #pragma unroll
            for (int m = 0; m < 2; ++m) {
                const int fe = m ? fe1 : fe0;
                const int dm = m ? dm1 : dm0;
                if (fe > 0) {
                    float p[4][4];
                    float pmax = -1e30f;
                    #pragma unroll
                    for (int f = 0; f < 4; ++f)
                        if (f < fe) {
                            f32x4 z = { 0.f, 0.f, 0.f, 0.f };
                            z = mfma16(kfa[f][0], qf[m][0], z);
                            z = mfma16(kfa[f][1], qf[m][1], z);
                            #pragma unroll
                            for (int reg = 0; reg < 4; ++reg) {
                                float sv = z[reg] * KSC;
                                if (f == dm) sv = (g * 4 + reg > r15) ? -1e30f : sv;
                                p[f][reg] = sv;
                                pmax = fmaxf(pmax, sv);
                            }
                        }
                    pmax = fmaxf(pmax, __shfl_xor(pmax, 16));
                    pmax = fmaxf(pmax, __shfl_xor(pmax, 32));
                    float newm = fmaxf(mrun[m], pmax);
                    float sc = fexp2(mrun[m] - newm);
                    float rsum = 0.f;
                    s16x4 pb[4];
                    #pragma unroll
                    for (int f = 0; f < 4; ++f)
                        if (f < fe)
                            #pragma unroll
                            for (int reg = 0; reg < 4; ++reg) {
                                float e = fexp2(p[f][reg] - newm);
                                rsum += e;
                                pb[f][reg] = f2bf(e);
                            }
                    rsum += __shfl_xor(rsum, 16);
                    rsum += __shfl_xor(rsum, 32);
                    lrun[m] = lrun[m] * sc + rsum;
                    mrun[m] = newm;
                    #pragma unroll
                    for (int f2 = 0; f2 < 4; ++f2) o[m][f2] *= sc;
                    #pragma unroll
                    for (int f2 = 0; f2 < 4; ++f2)
                        #pragma unroll
                        for (int f = 0; f < 4; ++f)
                            if (f < fe)
                                o[m][f2] = mfma16k16(vfa[f2][f], pb[f], o[m][f2]);
                }
            }
        }

        if (pre) {
            *(s16x8*)&Ks[cur ^ 1][r0][cx0]  = ka;
            *(s16x8*)&Ks[cur ^ 1][r1][cx1]  = kb;
            *(s16x8*)&Vts[cur ^ 1][r0][cx0] = va;
            *(s16x8*)&Vts[cur ^ 1][r1][cx1] = vb;
        }
        __syncthreads();
    }

    const int b = bh >> 4, h = bh & 15;
    #pragma unroll
    for (int m = 0; m < 2; ++m) {
        float inv = 1.f / (lrun[m] + 1e-8f);
        const int qg = q0 + m * 64 + w * 16 + r15;
        size_t obase = ((size_t)b * S_LEN + qg) * HID + h * HDIM + g * 4;
        #pragma unroll
        for (int f2 = 0; f2 < 4; ++f2) {
            s16x4 ov = { f2bf(o[m][f2][0] * inv), f2bf(o[m][f2][1] * inv),
                         f2bf(o[m][f2][2] * inv), f2bf(o[m][f2][3] * inv) };
            *(s16x4*)(attn_ws + obase + f2 * 16) = ov;
        }
    }
}

// ---------------------------------------------------------------------------
// Kernel 3: out = attn(bf16) @ wo.T  -> fp32 d_out (unchanged).
// ---------------------------------------------------------------------------
__global__ __launch_bounds__(256) void wo_gemm(
    const short* __restrict__ attn, const float* __restrict__ wo,
    float* __restrict__ out)
{
    __shared__ short As[128][32];
    __shared__ short Bs[128][32];
    const int t = threadIdx.x;
    const int lane = t & 63, w = t >> 6;
    const int g = lane >> 4, r15 = lane & 15;
    const int wm = w >> 1, wn = w & 1;
    const int bid = blockIdx.x;
    const int mt = bid & 31, nt = bid >> 5;
    const int m0 = mt * 128, n0 = nt * 128;
    const int arow = t >> 2, acol = (t & 3) * 8;
    const int srow = t >> 3, scol = (t & 7) * 4;

    f32x4 acc[4][4] = {};

    for (int k0 = 0; k0 < 1024; k0 += 32) {
        __syncthreads();
        #pragma unroll
        for (int i = 0; i < 2; ++i) {
            int row = arow + i * 64;
            *(s16x8*)&As[row][acol] =
                *(const s16x8*)(attn + (size_t)(m0 + row) * 1024 + k0 + acol);
        }
        #pragma unroll
        for (int i = 0; i < 4; ++i) {
            int row = srow + i * 32;
            float4 vb = *(const float4*)(wo + (size_t)(n0 + row) * 1024 + k0 + scol);
            s16x4 sb = { f2bf(vb.x), f2bf(vb.y), f2bf(vb.z), f2bf(vb.w) };
            *(s16x4*)&Bs[row][scol] = sb;
        }
        __syncthreads();
        s16x8 af[4], bfr[4];
        #pragma unroll
        for (int mi = 0; mi < 4; ++mi)
            af[mi] = *(const s16x8*)&As[wm * 64 + mi * 16 + r15][g * 8];
        #pragma unroll
        for (int ni = 0; ni < 4; ++ni)
            bfr[ni] = *(const s16x8*)&Bs[wn * 64 + ni * 16 + r15][g * 8];
        #pragma unroll
        for (int mi = 0; mi < 4; ++mi)
            #pragma unroll
            for (int ni = 0; ni < 4; ++ni)
                acc[mi][ni] = mfma16(af[mi], bfr[ni], acc[mi][ni]);
    }

    #pragma unroll
    for (int mi = 0; mi < 4; ++mi)
    #pragma unroll
    for (int ni = 0; ni < 4; ++ni) {
        #pragma unroll
        for (int reg = 0; reg < 4; ++reg) {
            int m = m0 + wm * 64 + mi * 16 + g * 4 + reg;
            int n = n0 + wn * 64 + ni * 16 + r15;
            out[(size_t)m * 1024 + n] = acc[mi][ni][reg];
        }
    }
}

extern "C" void kernel_launch(void* const* d_in, const int* in_sizes, int n_in,
                              void* d_out, int out_size, void* d_ws, size_t ws_size,
                              hipStream_t stream) {
    const float* x  = (const float*)d_in[0];
    const float* wq = (const float*)d_in[1];
    const float* wk = (const float*)d_in[2];
    const float* wv = (const float*)d_in[3];
    const float* wo = (const float*)d_in[4];
    float* out = (float*)d_out;

    const size_t ELEMS = (size_t)BATCH * S_LEN * HID;   // 4096*1024
    short* q_ws    = (short*)d_ws;
    short* k_ws    = q_ws + ELEMS;
    short* vt_ws   = k_ws + ELEMS;
    short* attn_ws = vt_ws + ELEMS;

    qkv_gemm<<<dim3(768), dim3(256), 0, stream>>>(x, wq, wk, wv, q_ws, k_ws, vt_ws);
    attn_kernel<<<dim3(512), dim3(256), 0, stream>>>(q_ws, k_ws, vt_ws, attn_ws);
    wo_gemm<<<dim3(256), dim3(256), 0, stream>>>(attn_ws, wo, out);
}

// Round 5
// 154.767 us; speedup vs baseline: 4.0770x; 1.2664x over previous
//
#include <hip/hip_runtime.h>
#include <hip/hip_bf16.h>

#define S_LEN 2048
#define NHEAD 16
#define HDIM 64
#define HID 1024
#define BATCH 2

typedef __attribute__((ext_vector_type(8))) short s16x8;
typedef __attribute__((ext_vector_type(4))) short s16x4;
typedef __attribute__((ext_vector_type(4))) float f32x4;

__device__ __forceinline__ short f2bf(float f) {
    union { __hip_bfloat16 b; short s; } u;
    u.b = __float2bfloat16(f);
    return u.s;
}
__device__ __forceinline__ float fexp2(float x) {
    return __builtin_amdgcn_exp2f(x);
}
__device__ __forceinline__ f32x4 mfma16(s16x8 a, s16x8 b, f32x4 c) {
    return __builtin_amdgcn_mfma_f32_16x16x32_bf16(a, b, c, 0, 0, 0);
}
__device__ __forceinline__ f32x4 mfma16k16(s16x4 a, s16x4 b, f32x4 c) {
    return __builtin_amdgcn_mfma_f32_16x16x16bf16_1k(a, b, c, 0, 0, 0);
}
__device__ __forceinline__ void gload16(const short* g, short* l) {
    __builtin_amdgcn_global_load_lds(
        (const __attribute__((address_space(1))) void*)g,
        (__attribute__((address_space(3))) void*)l, 16, 0, 0);
}

// ---------------------------------------------------------------------------
// Kernel 0: one-shot fp32 -> bf16 conversion of x and all weights.
// wcat = [wq; wk; wv] rows 0..3071.  HBM-bound, ~8us.
// ---------------------------------------------------------------------------
__global__ __launch_bounds__(256) void convert_kernel(
    const float* __restrict__ x,  const float* __restrict__ wq,
    const float* __restrict__ wk, const float* __restrict__ wv,
    const float* __restrict__ wo,
    short* __restrict__ xb, short* __restrict__ wcat, short* __restrict__ wob)
{
    const int F4X = 1048576, F4W = 262144;
    const int total = F4X + 4 * F4W;
    for (int i = blockIdx.x * blockDim.x + threadIdx.x; i < total;
         i += gridDim.x * blockDim.x) {
        const float4* s; short* d; int off;
        if (i < F4X)              { s = (const float4*)x;  d = xb;             off = i; }
        else if (i < F4X + F4W)   { s = (const float4*)wq; d = wcat;           off = i - F4X; }
        else if (i < F4X + 2*F4W) { s = (const float4*)wk; d = wcat + 1048576; off = i - (F4X + F4W); }
        else if (i < F4X + 3*F4W) { s = (const float4*)wv; d = wcat + 2097152; off = i - (F4X + 2*F4W); }
        else                      { s = (const float4*)wo; d = wob;            off = i - (F4X + 3*F4W); }
        float4 v = s[off];
        s16x4 o4 = { f2bf(v.x), f2bf(v.y), f2bf(v.z), f2bf(v.w) };
        *(s16x4*)(d + (size_t)off * 4) = o4;
    }
}

// ---------------------------------------------------------------------------
// Kernel 1: fused QKV GEMM, m97-structure: 128x128 tile, BK=64,
// global_load_lds width-16 staging, 2 barriers/K-step, 4 waves.
// Y = xb @ wcat.T ; epilogue scatters Q,K [b,h,s,d] and V^T [b,h,d,s] bf16.
// ---------------------------------------------------------------------------
__global__ __launch_bounds__(256) void qkv_gemm2(
    const short* __restrict__ xb, const short* __restrict__ wcat,
    short* __restrict__ q_ws, short* __restrict__ k_ws, short* __restrict__ vt_ws)
{
    __shared__ short As[128][64];
    __shared__ short Bs[128][64];
    const int t = threadIdx.x;
    const int lane = t & 63, w = t >> 6;
    const int g = lane >> 4, r15 = lane & 15;
    const int wm = w >> 1, wn = w & 1;
    const int bid = blockIdx.x;
    const int lb = (bid & 7) * 96 + (bid >> 3);       // XCD-chunked, 768%8==0
    const int mt = lb & 31, nt = lb >> 5;             // 32 x 24
    const int m0 = mt * 128, n0 = nt * 128;
    const int lrow = lane >> 3, lcol = (lane & 7) * 8;

    f32x4 acc[4][4] = {};

    for (int k0 = 0; k0 < 1024; k0 += 64) {
        __syncthreads();
        #pragma unroll
        for (int ch = 0; ch < 4; ++ch) {
            const int row = w * 32 + ch * 8;          // wave-uniform
            gload16(xb   + (size_t)(m0 + row + lrow) * 1024 + k0 + lcol, &As[row][0]);
            gload16(wcat + (size_t)(n0 + row + lrow) * 1024 + k0 + lcol, &Bs[row][0]);
        }
        __syncthreads();
        #pragma unroll
        for (int kk = 0; kk < 2; ++kk) {
            s16x8 af[4], bfr[4];
            #pragma unroll
            for (int mi = 0; mi < 4; ++mi)
                af[mi] = *(const s16x8*)&As[wm * 64 + mi * 16 + r15][kk * 32 + g * 8];
            #pragma unroll
            for (int ni = 0; ni < 4; ++ni)
                bfr[ni] = *(const s16x8*)&Bs[wn * 64 + ni * 16 + r15][kk * 32 + g * 8];
            #pragma unroll
            for (int mi = 0; mi < 4; ++mi)
                #pragma unroll
                for (int ni = 0; ni < 4; ++ni)
                    acc[mi][ni] = mfma16(af[mi], bfr[ni], acc[mi][ni]);
        }
    }

    #pragma unroll
    for (int mi = 0; mi < 4; ++mi)
    #pragma unroll
    for (int ni = 0; ni < 4; ++ni) {
        f32x4 v = acc[mi][ni];
        #pragma unroll
        for (int reg = 0; reg < 4; ++reg) {
            int m  = m0 + wm * 64 + mi * 16 + g * 4 + reg;
            int ng = n0 + wn * 64 + ni * 16 + r15;
            int sel = ng >> 10;
            int nn = ng & 1023;
            int b = m >> 11, s = m & 2047;
            int h = nn >> 6, d = nn & 63;
            short val = f2bf(v[reg]);
            if (sel == 0)
                q_ws[((size_t)(b * NHEAD + h) * S_LEN + s) * HDIM + d] = val;
            else if (sel == 1)
                k_ws[((size_t)(b * NHEAD + h) * S_LEN + s) * HDIM + d] = val;
            else
                vt_ws[((size_t)(b * NHEAD + h) * HDIM + d) * S_LEN + s] = val;
        }
    }
}

// ---------------------------------------------------------------------------
// Kernel 2: causal flash attention with UNIFORM-WORK PAIRING.
// Block <- pair (p, 31-p) of 64-row q-tiles processed sequentially:
// work = (p+1) + (32-p) = 33 KV-tiles for every block -> 512 equal blocks.
// 4 waves x 16 q-rows; K/V^T double-buffered XOR-swizzled LDS; split staging.
// Swapped QK^T (16x16x32); PV via 16x16x16 (P C-layout == its B-frag layout).
// ---------------------------------------------------------------------------
__global__ __launch_bounds__(256) void attn_kernel2(
    const short* __restrict__ q_ws, const short* __restrict__ k_ws,
    const short* __restrict__ vt_ws, short* __restrict__ attn_ws)
{
    __shared__ short Ks[2][64][64];
    __shared__ short Vts[2][64][64];
    const int t = threadIdx.x;
    const int lane = t & 63, w = t >> 6;
    const int g = lane >> 4, r15 = lane & 15;
    const int bid = blockIdx.x;
    const int lb = (bid & 7) * 64 + (bid >> 3);   // XCD-chunked, 512%8==0
    const int p = lb & 15;
    const int bh = lb >> 4;
    const size_t base = (size_t)bh * S_LEN * HDIM;
    const float KSC = 0.18033688f;                // 0.125 * log2(e)
    const int swr = (r15 & 7) << 3;
    const int r0 = t >> 3, c0 = (t & 7) * 8;
    const int cx0 = c0 ^ ((r0 & 7) << 3);
    const int b = bh >> 4, h = bh & 15;

    for (int phase = 0; phase < 2; ++phase) {
        const int qt = phase ? (31 - p) : p;
        const int q0 = qt * 64;
        const int ntk = qt + 1;
        const int qg = q0 + w * 16 + r15;
        s16x8 qf0 = *(const s16x8*)(q_ws + base + (size_t)qg * HDIM + g * 8);
        s16x8 qf1 = *(const s16x8*)(q_ws + base + (size_t)qg * HDIM + 32 + g * 8);
        f32x4 o[4] = {};
        float mrun = -1e30f, lrun = 0.f;

        // prologue: stage KV tile 0 into buffer 0
        *(s16x8*)&Ks[0][r0][cx0]        = *(const s16x8*)(k_ws  + base + (size_t)r0 * HDIM + c0);
        *(s16x8*)&Ks[0][r0 + 32][cx0]   = *(const s16x8*)(k_ws  + base + (size_t)(r0 + 32) * HDIM + c0);
        *(s16x8*)&Vts[0][r0][cx0]       = *(const s16x8*)(vt_ws + base + (size_t)r0 * S_LEN + c0);
        *(s16x8*)&Vts[0][r0 + 32][cx0]  = *(const s16x8*)(vt_ws + base + (size_t)(r0 + 32) * S_LEN + c0);
        __syncthreads();

        for (int kt = 0; kt < ntk; ++kt) {
            const int cur = kt & 1;
            const bool pre = (kt + 1 < ntk);
            s16x8 ka, kb, va, vb;
            if (pre) {
                const int kn = (kt + 1) * 64;
                ka = *(const s16x8*)(k_ws  + base + (size_t)(kn + r0) * HDIM + c0);
                kb = *(const s16x8*)(k_ws  + base + (size_t)(kn + r0 + 32) * HDIM + c0);
                va = *(const s16x8*)(vt_ws + base + (size_t)r0 * S_LEN + kn + c0);
                vb = *(const s16x8*)(vt_ws + base + (size_t)(r0 + 32) * S_LEN + kn + c0);
            }
            const bool dg = (kt == ntk - 1);
            const int fend = dg ? (w + 1) : 4;

            s16x8 kfa[4][2];
            s16x4 vfa[4][4];
            #pragma unroll
            for (int f = 0; f < 4; ++f)
                if (f < fend)
                    #pragma unroll
                    for (int c = 0; c < 2; ++c)
                        kfa[f][c] = *(const s16x8*)&Ks[cur][f * 16 + r15][(c * 32 + g * 8) ^ swr];
            #pragma unroll
            for (int f2 = 0; f2 < 4; ++f2)
                #pragma unroll
                for (int f = 0; f < 4; ++f)
                    if (f < fend)
                        vfa[f2][f] = *(const s16x4*)&Vts[cur][f2 * 16 + r15][(f * 16 + g * 4) ^ swr];

            float pv[4][4];
            float pmax = -1e30f;
            __builtin_amdgcn_s_setprio(1);
            #pragma unroll
            for (int f = 0; f < 4; ++f)
                if (f < fend) {
                    f32x4 z = { 0.f, 0.f, 0.f, 0.f };
                    z = mfma16(kfa[f][0], qf0, z);
                    z = mfma16(kfa[f][1], qf1, z);
                    #pragma unroll
                    for (int reg = 0; reg < 4; ++reg) {
                        float sv = z[reg] * KSC;
                        if (dg && f == w) sv = (g * 4 + reg > r15) ? -1e30f : sv;
                        pv[f][reg] = sv;
                        pmax = fmaxf(pmax, sv);
                    }
                }
            __builtin_amdgcn_s_setprio(0);
            pmax = fmaxf(pmax, __shfl_xor(pmax, 16));
            pmax = fmaxf(pmax, __shfl_xor(pmax, 32));
            float newm = fmaxf(mrun, pmax);
            float sc = fexp2(mrun - newm);
            float rsum = 0.f;
            s16x4 pb[4];
            #pragma unroll
            for (int f = 0; f < 4; ++f)
                if (f < fend)
                    #pragma unroll
                    for (int reg = 0; reg < 4; ++reg) {
                        float e = fexp2(pv[f][reg] - newm);
                        rsum += e;
                        pb[f][reg] = f2bf(e);
                    }
            rsum += __shfl_xor(rsum, 16);
            rsum += __shfl_xor(rsum, 32);
            lrun = lrun * sc + rsum;
            mrun = newm;
            #pragma unroll
            for (int f2 = 0; f2 < 4; ++f2) o[f2] *= sc;

            __builtin_amdgcn_s_setprio(1);
            #pragma unroll
            for (int f2 = 0; f2 < 4; ++f2)
                #pragma unroll
                for (int f = 0; f < 4; ++f)
                    if (f < fend)
                        o[f2] = mfma16k16(vfa[f2][f], pb[f], o[f2]);
            __builtin_amdgcn_s_setprio(0);

            if (pre) {
                *(s16x8*)&Ks[cur ^ 1][r0][cx0]       = ka;
                *(s16x8*)&Ks[cur ^ 1][r0 + 32][cx0]  = kb;
                *(s16x8*)&Vts[cur ^ 1][r0][cx0]      = va;
                *(s16x8*)&Vts[cur ^ 1][r0 + 32][cx0] = vb;
            }
            __syncthreads();
        }

        float inv = 1.f / (lrun + 1e-8f);
        size_t obase = ((size_t)b * S_LEN + qg) * HID + h * HDIM + g * 4;
        #pragma unroll
        for (int f2 = 0; f2 < 4; ++f2) {
            s16x4 ov = { f2bf(o[f2][0] * inv), f2bf(o[f2][1] * inv),
                         f2bf(o[f2][2] * inv), f2bf(o[f2][3] * inv) };
            *(s16x4*)(attn_ws + obase + f2 * 16) = ov;
        }
    }
}

// ---------------------------------------------------------------------------
// Kernel 3: out = attn(bf16) @ wob.T -> fp32, m97-structure like qkv_gemm2.
// ---------------------------------------------------------------------------
__global__ __launch_bounds__(256) void wo_gemm2(
    const short* __restrict__ attn, const short* __restrict__ wob,
    float* __restrict__ out)
{
    __shared__ short As[128][64];
    __shared__ short Bs[128][64];
    const int t = threadIdx.x;
    const int lane = t & 63, w = t >> 6;
    const int g = lane >> 4, r15 = lane & 15;
    const int wm = w >> 1, wn = w & 1;
    const int bid = blockIdx.x;
    const int lb = (bid & 7) * 32 + (bid >> 3);       // 256%8==0
    const int mt = lb & 31, nt = lb >> 5;             // 32 x 8
    const int m0 = mt * 128, n0 = nt * 128;
    const int lrow = lane >> 3, lcol = (lane & 7) * 8;

    f32x4 acc[4][4] = {};

    for (int k0 = 0; k0 < 1024; k0 += 64) {
        __syncthreads();
        #pragma unroll
        for (int ch = 0; ch < 4; ++ch) {
            const int row = w * 32 + ch * 8;
            gload16(attn + (size_t)(m0 + row + lrow) * 1024 + k0 + lcol, &As[row][0]);
            gload16(wob  + (size_t)(n0 + row + lrow) * 1024 + k0 + lcol, &Bs[row][0]);
        }
        __syncthreads();
        #pragma unroll
        for (int kk = 0; kk < 2; ++kk) {
            s16x8 af[4], bfr[4];
            #pragma unroll
            for (int mi = 0; mi < 4; ++mi)
                af[mi] = *(const s16x8*)&As[wm * 64 + mi * 16 + r15][kk * 32 + g * 8];
            #pragma unroll
            for (int ni = 0; ni < 4; ++ni)
                bfr[ni] = *(const s16x8*)&Bs[wn * 64 + ni * 16 + r15][kk * 32 + g * 8];
            #pragma unroll
            for (int mi = 0; mi < 4; ++mi)
                #pragma unroll
                for (int ni = 0; ni < 4; ++ni)
                    acc[mi][ni] = mfma16(af[mi], bfr[ni], acc[mi][ni]);
        }
    }

    #pragma unroll
    for (int mi = 0; mi < 4; ++mi)
    #pragma unroll
    for (int ni = 0; ni < 4; ++ni) {
        #pragma unroll
        for (int reg = 0; reg < 4; ++reg) {
            int m = m0 + wm * 64 + mi * 16 + g * 4 + reg;
            int n = n0 + wn * 64 + ni * 16 + r15;
            out[(size_t)m * 1024 + n] = acc[mi][ni][reg];
        }
    }
}

extern "C" void kernel_launch(void* const* d_in, const int* in_sizes, int n_in,
                              void* d_out, int out_size, void* d_ws, size_t ws_size,
                              hipStream_t stream) {
    const float* x  = (const float*)d_in[0];
    const float* wq = (const float*)d_in[1];
    const float* wk = (const float*)d_in[2];
    const float* wv = (const float*)d_in[3];
    const float* wo = (const float*)d_in[4];
    float* out = (float*)d_out;

    const size_t ELEMS = (size_t)BATCH * S_LEN * HID;   // 4,194,304
    short* q_ws    = (short*)d_ws;
    short* k_ws    = q_ws + ELEMS;
    short* vt_ws   = k_ws + ELEMS;
    short* xb      = vt_ws + ELEMS;        // aliased: xb (k0/k1) then attn (k2/k3)
    short* attn_ws = xb;
    short* wcat    = xb + ELEMS;           // 3,145,728
    short* wob     = wcat + 3145728;       // 1,048,576   total ~42MB

    convert_kernel<<<dim3(2048), dim3(256), 0, stream>>>(x, wq, wk, wv, wo, xb, wcat, wob);
    qkv_gemm2<<<dim3(768), dim3(256), 0, stream>>>(xb, wcat, q_ws, k_ws, vt_ws);
    attn_kernel2<<<dim3(512), dim3(256), 0, stream>>>(q_ws, k_ws, vt_ws, attn_ws);
    wo_gemm2<<<dim3(256), dim3(256), 0, stream>>>(attn_ws, wob, out);
}

// Round 6
// 124.673 us; speedup vs baseline: 5.0612x; 1.2414x over previous
//
#include <hip/hip_runtime.h>
#include <hip/hip_bf16.h>

#define S_LEN 2048
#define NHEAD 16
#define HDIM 64
#define HID 1024
#define BATCH 2
#define TSTR 136   // T-buffer stride (shorts): 272B rows, 16B-aligned, banks rotate by 4/row

typedef __attribute__((ext_vector_type(8))) short s16x8;
typedef __attribute__((ext_vector_type(4))) short s16x4;
typedef __attribute__((ext_vector_type(4))) float f32x4;

__device__ __forceinline__ short f2bf(float f) {
    union { __hip_bfloat16 b; short s; } u;
    u.b = __float2bfloat16(f);
    return u.s;
}
__device__ __forceinline__ float fexp2(float x) {
    return __builtin_amdgcn_exp2f(x);
}
__device__ __forceinline__ f32x4 mfma16(s16x8 a, s16x8 b, f32x4 c) {
    return __builtin_amdgcn_mfma_f32_16x16x32_bf16(a, b, c, 0, 0, 0);
}
__device__ __forceinline__ f32x4 mfma16k16(s16x4 a, s16x4 b, f32x4 c) {
    return __builtin_amdgcn_mfma_f32_16x16x16bf16_1k(a, b, c, 0, 0, 0);
}
__device__ __forceinline__ void gload16(const short* g, short* l) {
    __builtin_amdgcn_global_load_lds(
        (const __attribute__((address_space(1))) void*)g,
        (__attribute__((address_space(3))) void*)l, 16, 0, 0);
}

// ---------------------------------------------------------------------------
// Kernel 0: one-shot fp32 -> bf16 conversion of x and all weights.
// ---------------------------------------------------------------------------
__global__ __launch_bounds__(256) void convert_kernel(
    const float* __restrict__ x,  const float* __restrict__ wq,
    const float* __restrict__ wk, const float* __restrict__ wv,
    const float* __restrict__ wo,
    short* __restrict__ xb, short* __restrict__ wcat, short* __restrict__ wob)
{
    const int F4X = 1048576, F4W = 262144;
    const int total = F4X + 4 * F4W;
    for (int i = blockIdx.x * blockDim.x + threadIdx.x; i < total;
         i += gridDim.x * blockDim.x) {
        const float4* s; short* d; int off;
        if (i < F4X)              { s = (const float4*)x;  d = xb;             off = i; }
        else if (i < F4X + F4W)   { s = (const float4*)wq; d = wcat;           off = i - F4X; }
        else if (i < F4X + 2*F4W) { s = (const float4*)wk; d = wcat + 1048576; off = i - (F4X + F4W); }
        else if (i < F4X + 3*F4W) { s = (const float4*)wv; d = wcat + 2097152; off = i - (F4X + 2*F4W); }
        else                      { s = (const float4*)wo; d = wob;            off = i - (F4X + 3*F4W); }
        float4 v = s[off];
        s16x4 o4 = { f2bf(v.x), f2bf(v.y), f2bf(v.z), f2bf(v.w) };
        *(s16x4*)(d + (size_t)off * 4) = o4;
    }
}

// ---------------------------------------------------------------------------
// Kernel 1: fused QKV GEMM. 128x128 tile, BK=64, global_load_lds staging with
// source-side XOR swizzle (rule #21: linear dest + inverse-swizzled source +
// swizzled read).  V blocks swap MFMA operands so C = [d][s]-major.
// Epilogue: C -> bf16 -> LDS T[128][136] -> fully coalesced 16B row writes.
// ---------------------------------------------------------------------------
__global__ __launch_bounds__(256) void qkv_gemm2(
    const short* __restrict__ xb, const short* __restrict__ wcat,
    short* __restrict__ q_ws, short* __restrict__ k_ws, short* __restrict__ vt_ws)
{
    __shared__ union SM {
        struct { short A[128][64]; short B[128][64]; } s;
        short T[128][TSTR];
    } sm;
    const int t = threadIdx.x;
    const int lane = t & 63, w = t >> 6;
    const int g = lane >> 4, r15 = lane & 15;
    const int wm = w >> 1, wn = w & 1;
    const int bid = blockIdx.x;
    // XCD-chunked, nt-inner: each XCD owns 4 mt rows, streams all 24 nt
    const int cx = bid & 7, ii = bid >> 3;            // ii 0..95
    const int mt = cx * 4 + (ii & 3), nt = ii >> 2;   // mt 0..31, nt 0..23
    const int m0 = mt * 128, n0 = nt * 128;
    const int sel = n0 >> 10;                         // 0=q,1=k,2=v
    const int nr0 = n0 & 1023;
    // operand swap for V: A <- wv rows, B <- x rows  => C rows = d, cols = s
    const short* Ag = (sel == 2) ? (wcat + (size_t)(2048 + nr0) * 1024)
                                 : (xb   + (size_t)m0 * 1024);
    const short* Bg = (sel == 2) ? (xb   + (size_t)m0 * 1024)
                                 : (wcat + (size_t)(sel * 1024 + nr0) * 1024);
    const int lrow = lane >> 3;                       // 0..7
    const int scol = ((lane & 7) ^ lrow) * 8;         // pre-swizzled source col
    const int rsw = r15 & 7;                          // read-side row swizzle

    f32x4 acc[4][4] = {};

    for (int k0 = 0; k0 < 1024; k0 += 64) {
        __syncthreads();
        #pragma unroll
        for (int ch = 0; ch < 4; ++ch) {
            const int row = w * 32 + ch * 8;          // wave-uniform base
            gload16(Ag + (size_t)(row + lrow) * 1024 + k0 + scol, &sm.s.A[row][0]);
            gload16(Bg + (size_t)(row + lrow) * 1024 + k0 + scol, &sm.s.B[row][0]);
        }
        __syncthreads();
        #pragma unroll
        for (int kk = 0; kk < 2; ++kk) {
            s16x8 af[4], bfr[4];
            #pragma unroll
            for (int mi = 0; mi < 4; ++mi)
                af[mi] = *(const s16x8*)&sm.s.A[wm * 64 + mi * 16 + r15][((kk * 4 + g) ^ rsw) * 8];
            #pragma unroll
            for (int ni = 0; ni < 4; ++ni)
                bfr[ni] = *(const s16x8*)&sm.s.B[wn * 64 + ni * 16 + r15][((kk * 4 + g) ^ rsw) * 8];
            #pragma unroll
            for (int mi = 0; mi < 4; ++mi)
                #pragma unroll
                for (int ni = 0; ni < 4; ++ni)
                    acc[mi][ni] = mfma16(af[mi], bfr[ni], acc[mi][ni]);
        }
    }

    // ---- reorder epilogue through LDS ----
    __syncthreads();                                  // protect stage readers
    #pragma unroll
    for (int mi = 0; mi < 4; ++mi)
    #pragma unroll
    for (int ni = 0; ni < 4; ++ni)
        #pragma unroll
        for (int reg = 0; reg < 4; ++reg)
            sm.T[wm * 64 + mi * 16 + g * 4 + reg][wn * 64 + ni * 16 + r15]
                = f2bf(acc[mi][ni][reg]);
    __syncthreads();

    const int b = m0 >> 11;
    const int ms = m0 & 2047;
    #pragma unroll
    for (int it = 0; it < 8; ++it) {
        int u = w + it * 4;                 // 0..31
        int half = u & 1;
        int rg = u >> 1;                    // 0..15
        int r = rg * 8 + lrow;              // 0..127
        int colc = half * 64 + (lane & 7) * 8;
        s16x8 v = *(const s16x8*)&sm.T[r][colc];
        if (sel == 2) {
            int n = nr0 + r;                // output-dim (head-d)
            int h = n >> 6, d = n & 63;
            *(s16x8*)(vt_ws + ((size_t)(b * NHEAD + h) * HDIM + d) * S_LEN + ms + colc) = v;
        } else {
            int s = ms + r;
            int n = nr0 + colc;
            int h = n >> 6, d = n & 63;
            short* dst = (sel == 0) ? q_ws : k_ws;
            *(s16x8*)(dst + ((size_t)(b * NHEAD + h) * S_LEN + s) * HDIM + d) = v;
        }
    }
}

// ---------------------------------------------------------------------------
// Kernel 2: causal flash attention with UNIFORM-WORK PAIRING (unchanged R5).
// ---------------------------------------------------------------------------
__global__ __launch_bounds__(256) void attn_kernel2(
    const short* __restrict__ q_ws, const short* __restrict__ k_ws,
    const short* __restrict__ vt_ws, short* __restrict__ attn_ws)
{
    __shared__ short Ks[2][64][64];
    __shared__ short Vts[2][64][64];
    const int t = threadIdx.x;
    const int lane = t & 63, w = t >> 6;
    const int g = lane >> 4, r15 = lane & 15;
    const int bid = blockIdx.x;
    const int lb = (bid & 7) * 64 + (bid >> 3);   // XCD-chunked, 512%8==0
    const int p = lb & 15;
    const int bh = lb >> 4;
    const size_t base = (size_t)bh * S_LEN * HDIM;
    const float KSC = 0.18033688f;                // 0.125 * log2(e)
    const int swr = (r15 & 7) << 3;
    const int r0 = t >> 3, c0 = (t & 7) * 8;
    const int cx0 = c0 ^ ((r0 & 7) << 3);
    const int b = bh >> 4, h = bh & 15;

    for (int phase = 0; phase < 2; ++phase) {
        const int qt = phase ? (31 - p) : p;
        const int q0 = qt * 64;
        const int ntk = qt + 1;
        const int qg = q0 + w * 16 + r15;
        s16x8 qf0 = *(const s16x8*)(q_ws + base + (size_t)qg * HDIM + g * 8);
        s16x8 qf1 = *(const s16x8*)(q_ws + base + (size_t)qg * HDIM + 32 + g * 8);
        f32x4 o[4] = {};
        float mrun = -1e30f, lrun = 0.f;

        *(s16x8*)&Ks[0][r0][cx0]        = *(const s16x8*)(k_ws  + base + (size_t)r0 * HDIM + c0);
        *(s16x8*)&Ks[0][r0 + 32][cx0]   = *(const s16x8*)(k_ws  + base + (size_t)(r0 + 32) * HDIM + c0);
        *(s16x8*)&Vts[0][r0][cx0]       = *(const s16x8*)(vt_ws + base + (size_t)r0 * S_LEN + c0);
        *(s16x8*)&Vts[0][r0 + 32][cx0]  = *(const s16x8*)(vt_ws + base + (size_t)(r0 + 32) * S_LEN + c0);
        __syncthreads();

        for (int kt = 0; kt < ntk; ++kt) {
            const int cur = kt & 1;
            const bool pre = (kt + 1 < ntk);
            s16x8 ka, kb, va, vb;
            if (pre) {
                const int kn = (kt + 1) * 64;
                ka = *(const s16x8*)(k_ws  + base + (size_t)(kn + r0) * HDIM + c0);
                kb = *(const s16x8*)(k_ws  + base + (size_t)(kn + r0 + 32) * HDIM + c0);
                va = *(const s16x8*)(vt_ws + base + (size_t)r0 * S_LEN + kn + c0);
                vb = *(const s16x8*)(vt_ws + base + (size_t)(r0 + 32) * S_LEN + kn + c0);
            }
            const bool dg = (kt == ntk - 1);
            const int fend = dg ? (w + 1) : 4;

            s16x8 kfa[4][2];
            s16x4 vfa[4][4];
            #pragma unroll
            for (int f = 0; f < 4; ++f)
                if (f < fend)
                    #pragma unroll
                    for (int c = 0; c < 2; ++c)
                        kfa[f][c] = *(const s16x8*)&Ks[cur][f * 16 + r15][(c * 32 + g * 8) ^ swr];
            #pragma unroll
            for (int f2 = 0; f2 < 4; ++f2)
                #pragma unroll
                for (int f = 0; f < 4; ++f)
                    if (f < fend)
                        vfa[f2][f] = *(const s16x4*)&Vts[cur][f2 * 16 + r15][(f * 16 + g * 4) ^ swr];

            float pv[4][4];
            float pmax = -1e30f;
            __builtin_amdgcn_s_setprio(1);
            #pragma unroll
            for (int f = 0; f < 4; ++f)
                if (f < fend) {
                    f32x4 z = { 0.f, 0.f, 0.f, 0.f };
                    z = mfma16(kfa[f][0], qf0, z);
                    z = mfma16(kfa[f][1], qf1, z);
                    #pragma unroll
                    for (int reg = 0; reg < 4; ++reg) {
                        float sv = z[reg] * KSC;
                        if (dg && f == w) sv = (g * 4 + reg > r15) ? -1e30f : sv;
                        pv[f][reg] = sv;
                        pmax = fmaxf(pmax, sv);
                    }
                }
            __builtin_amdgcn_s_setprio(0);
            pmax = fmaxf(pmax, __shfl_xor(pmax, 16));
            pmax = fmaxf(pmax, __shfl_xor(pmax, 32));
            float newm = fmaxf(mrun, pmax);
            float sc = fexp2(mrun - newm);
            float rsum = 0.f;
            s16x4 pb[4];
            #pragma unroll
            for (int f = 0; f < 4; ++f)
                if (f < fend)
                    #pragma unroll
                    for (int reg = 0; reg < 4; ++reg) {
                        float e = fexp2(pv[f][reg] - newm);
                        rsum += e;
                        pb[f][reg] = f2bf(e);
                    }
            rsum += __shfl_xor(rsum, 16);
            rsum += __shfl_xor(rsum, 32);
            lrun = lrun * sc + rsum;
            mrun = newm;
            #pragma unroll
            for (int f2 = 0; f2 < 4; ++f2) o[f2] *= sc;

            __builtin_amdgcn_s_setprio(1);
            #pragma unroll
            for (int f2 = 0; f2 < 4; ++f2)
                #pragma unroll
                for (int f = 0; f < 4; ++f)
                    if (f < fend)
                        o[f2] = mfma16k16(vfa[f2][f], pb[f], o[f2]);
            __builtin_amdgcn_s_setprio(0);

            if (pre) {
                *(s16x8*)&Ks[cur ^ 1][r0][cx0]       = ka;
                *(s16x8*)&Ks[cur ^ 1][r0 + 32][cx0]  = kb;
                *(s16x8*)&Vts[cur ^ 1][r0][cx0]      = va;
                *(s16x8*)&Vts[cur ^ 1][r0 + 32][cx0] = vb;
            }
            __syncthreads();
        }

        float inv = 1.f / (lrun + 1e-8f);
        size_t obase = ((size_t)b * S_LEN + qg) * HID + h * HDIM + g * 4;
        #pragma unroll
        for (int f2 = 0; f2 < 4; ++f2) {
            s16x4 ov = { f2bf(o[f2][0] * inv), f2bf(o[f2][1] * inv),
                         f2bf(o[f2][2] * inv), f2bf(o[f2][3] * inv) };
            *(s16x4*)(attn_ws + obase + f2 * 16) = ov;
        }
    }
}

// ---------------------------------------------------------------------------
// Kernel 3: out = attn(bf16) @ wob.T -> fp32.  Swizzled staging + reads.
// ---------------------------------------------------------------------------
__global__ __launch_bounds__(256) void wo_gemm2(
    const short* __restrict__ attn, const short* __restrict__ wob,
    float* __restrict__ out)
{
    __shared__ short As[128][64];
    __shared__ short Bs[128][64];
    const int t = threadIdx.x;
    const int lane = t & 63, w = t >> 6;
    const int g = lane >> 4, r15 = lane & 15;
    const int wm = w >> 1, wn = w & 1;
    const int bid = blockIdx.x;
    const int cx = bid & 7, ii = bid >> 3;            // ii 0..31
    const int mt = cx * 4 + (ii & 3), nt = ii >> 2;   // 32 x 8
    const int m0 = mt * 128, n0 = nt * 128;
    const int lrow = lane >> 3;
    const int scol = ((lane & 7) ^ lrow) * 8;
    const int rsw = r15 & 7;

    f32x4 acc[4][4] = {};

    for (int k0 = 0; k0 < 1024; k0 += 64) {
        __syncthreads();
        #pragma unroll
        for (int ch = 0; ch < 4; ++ch) {
            const int row = w * 32 + ch * 8;
            gload16(attn + (size_t)(m0 + row + lrow) * 1024 + k0 + scol, &As[row][0]);
            gload16(wob  + (size_t)(n0 + row + lrow) * 1024 + k0 + scol, &Bs[row][0]);
        }
        __syncthreads();
        #pragma unroll
        for (int kk = 0; kk < 2; ++kk) {
            s16x8 af[4], bfr[4];
            #pragma unroll
            for (int mi = 0; mi < 4; ++mi)
                af[mi] = *(const s16x8*)&As[wm * 64 + mi * 16 + r15][((kk * 4 + g) ^ rsw) * 8];
            #pragma unroll
            for (int ni = 0; ni < 4; ++ni)
                bfr[ni] = *(const s16x8*)&Bs[wn * 64 + ni * 16 + r15][((kk * 4 + g) ^ rsw) * 8];
            #pragma unroll
            for (int mi = 0; mi < 4; ++mi)
                #pragma unroll
                for (int ni = 0; ni < 4; ++ni)
                    acc[mi][ni] = mfma16(af[mi], bfr[ni], acc[mi][ni]);
        }
    }

    #pragma unroll
    for (int mi = 0; mi < 4; ++mi)
    #pragma unroll
    for (int ni = 0; ni < 4; ++ni) {
        #pragma unroll
        for (int reg = 0; reg < 4; ++reg) {
            int m = m0 + wm * 64 + mi * 16 + g * 4 + reg;
            int n = n0 + wn * 64 + ni * 16 + r15;
            out[(size_t)m * 1024 + n] = acc[mi][ni][reg];
        }
    }
}

extern "C" void kernel_launch(void* const* d_in, const int* in_sizes, int n_in,
                              void* d_out, int out_size, void* d_ws, size_t ws_size,
                              hipStream_t stream) {
    const float* x  = (const float*)d_in[0];
    const float* wq = (const float*)d_in[1];
    const float* wk = (const float*)d_in[2];
    const float* wv = (const float*)d_in[3];
    const float* wo = (const float*)d_in[4];
    float* out = (float*)d_out;

    const size_t ELEMS = (size_t)BATCH * S_LEN * HID;   // 4,194,304
    short* q_ws    = (short*)d_ws;
    short* k_ws    = q_ws + ELEMS;
    short* vt_ws   = k_ws + ELEMS;
    short* xb      = vt_ws + ELEMS;        // aliased: xb (k0/k1) then attn (k2/k3)
    short* attn_ws = xb;
    short* wcat    = xb + ELEMS;           // 3,145,728
    short* wob     = wcat + 3145728;       // 1,048,576   total ~42MB

    convert_kernel<<<dim3(2048), dim3(256), 0, stream>>>(x, wq, wk, wv, wo, xb, wcat, wob);
    qkv_gemm2<<<dim3(768), dim3(256), 0, stream>>>(xb, wcat, q_ws, k_ws, vt_ws);
    attn_kernel2<<<dim3(512), dim3(256), 0, stream>>>(q_ws, k_ws, vt_ws, attn_ws);
    wo_gemm2<<<dim3(256), dim3(256), 0, stream>>>(attn_ws, wob, out);
}

// Round 7
// 120.401 us; speedup vs baseline: 5.2407x; 1.0355x over previous
//
#include <hip/hip_runtime.h>
#include <hip/hip_bf16.h>

#define S_LEN 2048
#define NHEAD 16
#define HDIM 64
#define HID 1024
#define BATCH 2
#define TSTR 136   // T-buffer stride (shorts)

typedef __attribute__((ext_vector_type(8))) short s16x8;
typedef __attribute__((ext_vector_type(4))) short s16x4;
typedef __attribute__((ext_vector_type(4))) float f32x4;

__device__ __forceinline__ short f2bf(float f) {
    union { __hip_bfloat16 b; short s; } u;
    u.b = __float2bfloat16(f);
    return u.s;
}
__device__ __forceinline__ float fexp2(float x) {
    return __builtin_amdgcn_exp2f(x);
}
__device__ __forceinline__ f32x4 mfma16(s16x8 a, s16x8 b, f32x4 c) {
    return __builtin_amdgcn_mfma_f32_16x16x32_bf16(a, b, c, 0, 0, 0);
}
__device__ __forceinline__ void gload16(const short* g, short* l) {
    __builtin_amdgcn_global_load_lds(
        (const __attribute__((address_space(1))) void*)g,
        (__attribute__((address_space(3))) void*)l, 16, 0, 0);
}
// pack two f32 -> one u32 of 2 bf16 (round-half-up, inputs finite >=0)
__device__ __forceinline__ unsigned bfpack(float a, float b) {
    unsigned ua = __builtin_bit_cast(unsigned, a) + 0x8000u;
    unsigned ub = __builtin_bit_cast(unsigned, b) + 0x8000u;
    return (ub & 0xFFFF0000u) | (ua >> 16);
}

// ---------------------------------------------------------------------------
// Kernel 0: one-shot fp32 -> bf16 conversion of x and all weights.
// ---------------------------------------------------------------------------
__global__ __launch_bounds__(256) void convert_kernel(
    const float* __restrict__ x,  const float* __restrict__ wq,
    const float* __restrict__ wk, const float* __restrict__ wv,
    const float* __restrict__ wo,
    short* __restrict__ xb, short* __restrict__ wcat, short* __restrict__ wob)
{
    const int F4X = 1048576, F4W = 262144;
    const int total = F4X + 4 * F4W;
    for (int i = blockIdx.x * blockDim.x + threadIdx.x; i < total;
         i += gridDim.x * blockDim.x) {
        const float4* s; short* d; int off;
        if (i < F4X)              { s = (const float4*)x;  d = xb;             off = i; }
        else if (i < F4X + F4W)   { s = (const float4*)wq; d = wcat;           off = i - F4X; }
        else if (i < F4X + 2*F4W) { s = (const float4*)wk; d = wcat + 1048576; off = i - (F4X + F4W); }
        else if (i < F4X + 3*F4W) { s = (const float4*)wv; d = wcat + 2097152; off = i - (F4X + 2*F4W); }
        else                      { s = (const float4*)wo; d = wob;            off = i - (F4X + 3*F4W); }
        float4 v = s[off];
        s16x4 o4 = { f2bf(v.x), f2bf(v.y), f2bf(v.z), f2bf(v.w) };
        *(s16x4*)(d + (size_t)off * 4) = o4;
    }
}

// ---------------------------------------------------------------------------
// Kernel 1: fused QKV GEMM (unchanged from R6).
// ---------------------------------------------------------------------------
__global__ __launch_bounds__(256) void qkv_gemm2(
    const short* __restrict__ xb, const short* __restrict__ wcat,
    short* __restrict__ q_ws, short* __restrict__ k_ws, short* __restrict__ vt_ws)
{
    __shared__ union SM {
        struct { short A[128][64]; short B[128][64]; } s;
        short T[128][TSTR];
    } sm;
    const int t = threadIdx.x;
    const int lane = t & 63, w = t >> 6;
    const int g = lane >> 4, r15 = lane & 15;
    const int wm = w >> 1, wn = w & 1;
    const int bid = blockIdx.x;
    const int cx = bid & 7, ii = bid >> 3;
    const int mt = cx * 4 + (ii & 3), nt = ii >> 2;
    const int m0 = mt * 128, n0 = nt * 128;
    const int sel = n0 >> 10;
    const int nr0 = n0 & 1023;
    const short* Ag = (sel == 2) ? (wcat + (size_t)(2048 + nr0) * 1024)
                                 : (xb   + (size_t)m0 * 1024);
    const short* Bg = (sel == 2) ? (xb   + (size_t)m0 * 1024)
                                 : (wcat + (size_t)(sel * 1024 + nr0) * 1024);
    const int lrow = lane >> 3;
    const int scol = ((lane & 7) ^ lrow) * 8;
    const int rsw = r15 & 7;

    f32x4 acc[4][4] = {};

    for (int k0 = 0; k0 < 1024; k0 += 64) {
        __syncthreads();
        #pragma unroll
        for (int ch = 0; ch < 4; ++ch) {
            const int row = w * 32 + ch * 8;
            gload16(Ag + (size_t)(row + lrow) * 1024 + k0 + scol, &sm.s.A[row][0]);
            gload16(Bg + (size_t)(row + lrow) * 1024 + k0 + scol, &sm.s.B[row][0]);
        }
        __syncthreads();
        #pragma unroll
        for (int kk = 0; kk < 2; ++kk) {
            s16x8 af[4], bfr[4];
            #pragma unroll
            for (int mi = 0; mi < 4; ++mi)
                af[mi] = *(const s16x8*)&sm.s.A[wm * 64 + mi * 16 + r15][((kk * 4 + g) ^ rsw) * 8];
            #pragma unroll
            for (int ni = 0; ni < 4; ++ni)
                bfr[ni] = *(const s16x8*)&sm.s.B[wn * 64 + ni * 16 + r15][((kk * 4 + g) ^ rsw) * 8];
            #pragma unroll
            for (int mi = 0; mi < 4; ++mi)
                #pragma unroll
                for (int ni = 0; ni < 4; ++ni)
                    acc[mi][ni] = mfma16(af[mi], bfr[ni], acc[mi][ni]);
        }
    }

    __syncthreads();
    #pragma unroll
    for (int mi = 0; mi < 4; ++mi)
    #pragma unroll
    for (int ni = 0; ni < 4; ++ni)
        #pragma unroll
        for (int reg = 0; reg < 4; ++reg)
            sm.T[wm * 64 + mi * 16 + g * 4 + reg][wn * 64 + ni * 16 + r15]
                = f2bf(acc[mi][ni][reg]);
    __syncthreads();

    const int b = m0 >> 11;
    const int ms = m0 & 2047;
    #pragma unroll
    for (int it = 0; it < 8; ++it) {
        int u = w + it * 4;
        int half = u & 1;
        int rg = u >> 1;
        int r = rg * 8 + lrow;
        int colc = half * 64 + (lane & 7) * 8;
        s16x8 v = *(const s16x8*)&sm.T[r][colc];
        if (sel == 2) {
            int n = nr0 + r;
            int h = n >> 6, d = n & 63;
            *(s16x8*)(vt_ws + ((size_t)(b * NHEAD + h) * HDIM + d) * S_LEN + ms + colc) = v;
        } else {
            int s = ms + r;
            int n = nr0 + colc;
            int h = n >> 6, d = n & 63;
            short* dst = (sel == 0) ? q_ws : k_ws;
            *(s16x8*)(dst + ((size_t)(b * NHEAD + h) * S_LEN + s) * HDIM + d) = v;
        }
    }
}

// ---------------------------------------------------------------------------
// Kernel 2: causal flash attention, paired q-tiles (uniform work), dbuf LDS.
// This round: PV at K=32 via consistent k-permutation (8 MFMAs, no shuffles),
// fma-folded exp2 args, bit-packed P->bf16, deferred per-lane rsum,
// defer-max (T13), uniform masked diagonal.
// ---------------------------------------------------------------------------
__global__ __launch_bounds__(256) void attn_kernel2(
    const short* __restrict__ q_ws, const short* __restrict__ k_ws,
    const short* __restrict__ vt_ws, short* __restrict__ attn_ws)
{
    __shared__ short Ks[2][64][64];
    __shared__ short Vts[2][64][64];
    const int t = threadIdx.x;
    const int lane = t & 63, w = t >> 6;
    const int g = lane >> 4, r15 = lane & 15;
    const int bid = blockIdx.x;
    const int lb = (bid & 7) * 64 + (bid >> 3);   // XCD-chunked, 512%8==0
    const int p = lb & 15;
    const int bh = lb >> 4;
    const size_t base = (size_t)bh * S_LEN * HDIM;
    const float KSC = 0.18033688f;                // 0.125 * log2(e)
    const int swr = (r15 & 7) << 3;
    const int r0 = t >> 3, c0 = (t & 7) * 8;
    const int cx0 = c0 ^ ((r0 & 7) << 3);
    const int b = bh >> 4, h = bh & 15;
    const int qloc = w * 16 + r15;                // q position within 64-tile

    union P8 { unsigned u[4]; s16x8 v; };
    union V8 { s16x4 h[2]; s16x8 v; };

    for (int phase = 0; phase < 2; ++phase) {
        const int qt = phase ? (31 - p) : p;
        const int q0 = qt * 64;
        const int ntk = qt + 1;
        const int qg = q0 + qloc;
        s16x8 qf0 = *(const s16x8*)(q_ws + base + (size_t)qg * HDIM + g * 8);
        s16x8 qf1 = *(const s16x8*)(q_ws + base + (size_t)qg * HDIM + 32 + g * 8);
        f32x4 o[4] = {};
        float mrun = -1e30f, lrun_p = 0.f;

        // prologue: stage KV tile 0 into buffer 0
        *(s16x8*)&Ks[0][r0][cx0]        = *(const s16x8*)(k_ws  + base + (size_t)r0 * HDIM + c0);
        *(s16x8*)&Ks[0][r0 + 32][cx0]   = *(const s16x8*)(k_ws  + base + (size_t)(r0 + 32) * HDIM + c0);
        *(s16x8*)&Vts[0][r0][cx0]       = *(const s16x8*)(vt_ws + base + (size_t)r0 * S_LEN + c0);
        *(s16x8*)&Vts[0][r0 + 32][cx0]  = *(const s16x8*)(vt_ws + base + (size_t)(r0 + 32) * S_LEN + c0);
        __syncthreads();

        // running prefetch pointers (tile 1)
        const short* kpa = k_ws  + base + (size_t)(64 + r0) * HDIM + c0;
        const short* kpb = kpa + 32 * HDIM;
        const short* vpa = vt_ws + base + (size_t)r0 * S_LEN + 64 + c0;
        const short* vpb = vpa + 32 * S_LEN;

        for (int kt = 0; kt < ntk; ++kt) {
            const int cur = kt & 1;
            const bool pre = (kt + 1 < ntk);
            const bool dg = (kt == ntk - 1);
            s16x8 ka, kb, va, vb;
            if (pre) {
                ka = *(const s16x8*)kpa;  kb = *(const s16x8*)kpb;
                va = *(const s16x8*)vpa;  vb = *(const s16x8*)vpb;
                kpa += 64 * HDIM; kpb += 64 * HDIM; vpa += 64; vpb += 64;
            }

            // ---- LDS fragment reads (issued together, hidden under QK/SM) ----
            s16x8 kfa[4][2];
            #pragma unroll
            for (int f = 0; f < 4; ++f)
                #pragma unroll
                for (int c = 0; c < 2; ++c)
                    kfa[f][c] = *(const s16x8*)&Ks[cur][f * 16 + r15][(c * 32 + g * 8) ^ swr];
            V8 vfr[4][2];
            #pragma unroll
            for (int f2 = 0; f2 < 4; ++f2)
                #pragma unroll
                for (int kc = 0; kc < 2; ++kc) {
                    vfr[f2][kc].h[0] = *(const s16x4*)&Vts[cur][f2 * 16 + r15][(kc * 32 + g * 4) ^ swr];
                    vfr[f2][kc].h[1] = *(const s16x4*)&Vts[cur][f2 * 16 + r15][(kc * 32 + 16 + g * 4) ^ swr];
                }

            // ---- QK^T ----
            f32x4 z[4];
            __builtin_amdgcn_s_setprio(1);
            #pragma unroll
            for (int f = 0; f < 4; ++f) {
                f32x4 zz = { 0.f, 0.f, 0.f, 0.f };
                zz = mfma16(kfa[f][0], qf0, zz);
                zz = mfma16(kfa[f][1], qf1, zz);
                z[f] = zz;
            }
            __builtin_amdgcn_s_setprio(0);

            // ---- causal mask (diagonal tile only) ----
            if (dg) {
                #pragma unroll
                for (int f = 0; f < 4; ++f)
                    #pragma unroll
                    for (int reg = 0; reg < 4; ++reg)
                        if (f * 16 + g * 4 + reg > qloc) z[f][reg] = -3e30f;
            }

            // ---- tree max + column reduce ----
            float zf[4];
            #pragma unroll
            for (int f = 0; f < 4; ++f)
                zf[f] = fmaxf(fmaxf(z[f][0], z[f][1]), fmaxf(z[f][2], z[f][3]));
            float zm = fmaxf(fmaxf(zf[0], zf[1]), fmaxf(zf[2], zf[3]));
            zm = fmaxf(zm, __shfl_xor(zm, 16));
            zm = fmaxf(zm, __shfl_xor(zm, 32));
            float pm = zm * KSC;

            // ---- defer-max (T13): rescale only when needed ----
            if (!__all(pm - mrun <= 8.0f)) {
                float newm = fmaxf(mrun, pm);
                float sc = fexp2(mrun - newm);
                #pragma unroll
                for (int f2 = 0; f2 < 4; ++f2) o[f2] *= sc;
                lrun_p *= sc;
                mrun = newm;
            }

            // ---- exp2 + pack + per-lane rsum ----
            P8 p8[2];
            #pragma unroll
            for (int f = 0; f < 4; ++f) {
                float e0 = fexp2(__builtin_fmaf(z[f][0], KSC, -mrun));
                float e1 = fexp2(__builtin_fmaf(z[f][1], KSC, -mrun));
                float e2 = fexp2(__builtin_fmaf(z[f][2], KSC, -mrun));
                float e3 = fexp2(__builtin_fmaf(z[f][3], KSC, -mrun));
                lrun_p += (e0 + e1) + (e2 + e3);
                p8[f >> 1].u[(f & 1) * 2]     = bfpack(e0, e1);
                p8[f >> 1].u[(f & 1) * 2 + 1] = bfpack(e2, e3);
            }

            // ---- PV at K=32, consistent k-permutation on both operands ----
            __builtin_amdgcn_s_setprio(1);
            #pragma unroll
            for (int f2 = 0; f2 < 4; ++f2) {
                o[f2] = mfma16(vfr[f2][0].v, p8[0].v, o[f2]);
                o[f2] = mfma16(vfr[f2][1].v, p8[1].v, o[f2]);
            }
            __builtin_amdgcn_s_setprio(0);

            if (pre) {
                *(s16x8*)&Ks[cur ^ 1][r0][cx0]       = ka;
                *(s16x8*)&Ks[cur ^ 1][r0 + 32][cx0]  = kb;
                *(s16x8*)&Vts[cur ^ 1][r0][cx0]      = va;
                *(s16x8*)&Vts[cur ^ 1][r0 + 32][cx0] = vb;
            }
            __syncthreads();
        }

        // ---- deferred column reduce of l, normalize, write ----
        float lr = lrun_p;
        lr += __shfl_xor(lr, 16);
        lr += __shfl_xor(lr, 32);
        float inv = 1.f / (lr + 1e-8f);
        size_t obase = ((size_t)b * S_LEN + qg) * HID + h * HDIM + g * 4;
        #pragma unroll
        for (int f2 = 0; f2 < 4; ++f2) {
            s16x4 ov = { f2bf(o[f2][0] * inv), f2bf(o[f2][1] * inv),
                         f2bf(o[f2][2] * inv), f2bf(o[f2][3] * inv) };
            *(s16x4*)(attn_ws + obase + f2 * 16) = ov;
        }
    }
}

// ---------------------------------------------------------------------------
// Kernel 3: out = attn(bf16) @ wob.T -> fp32 (unchanged from R6).
// ---------------------------------------------------------------------------
__global__ __launch_bounds__(256) void wo_gemm2(
    const short* __restrict__ attn, const short* __restrict__ wob,
    float* __restrict__ out)
{
    __shared__ short As[128][64];
    __shared__ short Bs[128][64];
    const int t = threadIdx.x;
    const int lane = t & 63, w = t >> 6;
    const int g = lane >> 4, r15 = lane & 15;
    const int wm = w >> 1, wn = w & 1;
    const int bid = blockIdx.x;
    const int cx = bid & 7, ii = bid >> 3;
    const int mt = cx * 4 + (ii & 3), nt = ii >> 2;
    const int m0 = mt * 128, n0 = nt * 128;
    const int lrow = lane >> 3;
    const int scol = ((lane & 7) ^ lrow) * 8;
    const int rsw = r15 & 7;

    f32x4 acc[4][4] = {};

    for (int k0 = 0; k0 < 1024; k0 += 64) {
        __syncthreads();
        #pragma unroll
        for (int ch = 0; ch < 4; ++ch) {
            const int row = w * 32 + ch * 8;
            gload16(attn + (size_t)(m0 + row + lrow) * 1024 + k0 + scol, &As[row][0]);
            gload16(wob  + (size_t)(n0 + row + lrow) * 1024 + k0 + scol, &Bs[row][0]);
        }
        __syncthreads();
        #pragma unroll
        for (int kk = 0; kk < 2; ++kk) {
            s16x8 af[4], bfr[4];
            #pragma unroll
            for (int mi = 0; mi < 4; ++mi)
                af[mi] = *(const s16x8*)&As[wm * 64 + mi * 16 + r15][((kk * 4 + g) ^ rsw) * 8];
            #pragma unroll
            for (int ni = 0; ni < 4; ++ni)
                bfr[ni] = *(const s16x8*)&Bs[wn * 64 + ni * 16 + r15][((kk * 4 + g) ^ rsw) * 8];
            #pragma unroll
            for (int mi = 0; mi < 4; ++mi)
                #pragma unroll
                for (int ni = 0; ni < 4; ++ni)
                    acc[mi][ni] = mfma16(af[mi], bfr[ni], acc[mi][ni]);
        }
    }

    #pragma unroll
    for (int mi = 0; mi < 4; ++mi)
    #pragma unroll
    for (int ni = 0; ni < 4; ++ni) {
        #pragma unroll
        for (int reg = 0; reg < 4; ++reg) {
            int m = m0 + wm * 64 + mi * 16 + g * 4 + reg;
            int n = n0 + wn * 64 + ni * 16 + r15;
            out[(size_t)m * 1024 + n] = acc[mi][ni][reg];
        }
    }
}

extern "C" void kernel_launch(void* const* d_in, const int* in_sizes, int n_in,
                              void* d_out, int out_size, void* d_ws, size_t ws_size,
                              hipStream_t stream) {
    const float* x  = (const float*)d_in[0];
    const float* wq = (const float*)d_in[1];
    const float* wk = (const float*)d_in[2];
    const float* wv = (const float*)d_in[3];
    const float* wo = (const float*)d_in[4];
    float* out = (float*)d_out;

    const size_t ELEMS = (size_t)BATCH * S_LEN * HID;   // 4,194,304
    short* q_ws    = (short*)d_ws;
    short* k_ws    = q_ws + ELEMS;
    short* vt_ws   = k_ws + ELEMS;
    short* xb      = vt_ws + ELEMS;        // aliased: xb (k0/k1) then attn (k2/k3)
    short* attn_ws = xb;
    short* wcat    = xb + ELEMS;           // 3,145,728
    short* wob     = wcat + 3145728;       // 1,048,576   total ~42MB

    convert_kernel<<<dim3(2048), dim3(256), 0, stream>>>(x, wq, wk, wv, wo, xb, wcat, wob);
    qkv_gemm2<<<dim3(768), dim3(256), 0, stream>>>(xb, wcat, q_ws, k_ws, vt_ws);
    attn_kernel2<<<dim3(512), dim3(256), 0, stream>>>(q_ws, k_ws, vt_ws, attn_ws);
    wo_gemm2<<<dim3(256), dim3(256), 0, stream>>>(attn_ws, wob, out);
}